// Round 2
// baseline (815.700 us; speedup 1.0000x reference)
//
#include <hip/hip_runtime.h>
#include <math.h>

#define T_SEQ 1024
#define NH 16
#define HD 64

typedef __attribute__((ext_vector_type(8))) short bf16x8;
typedef __attribute__((ext_vector_type(4))) float f32x4;

// monotone float -> uint key: a<b (float) <=> fkey(a)<fkey(b) (uint)
__device__ __forceinline__ unsigned fkey(float x) {
  unsigned u = __float_as_uint(x);
  return (u & 0x80000000u) ? ~u : (u | 0x80000000u);
}

__device__ __forceinline__ float wredmax(float v) {
#pragma unroll
  for (int m = 1; m < 64; m <<= 1) v = fmaxf(v, __shfl_xor(v, m));
  return v;
}
__device__ __forceinline__ float wredsum(float v) {
#pragma unroll
  for (int m = 1; m < 64; m <<= 1) v += __shfl_xor(v, m);
  return v;
}

// fp32 -> bf16 round-to-nearest-even (finite inputs)
__device__ __forceinline__ unsigned short f2bf(float f) {
  unsigned u = __float_as_uint(f);
  return (unsigned short)((u + 0x7fffu + ((u >> 16) & 1u)) >> 16);
}
__device__ __forceinline__ float bf2f(unsigned short h) {
  return __uint_as_float(((unsigned)h) << 16);
}

// async global->LDS, 16B/lane (LDS dest = wave-uniform base + lane*16)
__device__ __forceinline__ void gl_lds16(const void* g, void* l) {
  __builtin_amdgcn_global_load_lds(
      (const __attribute__((address_space(1))) unsigned int*)g,
      (__attribute__((address_space(3))) unsigned int*)l,
      16, 0, 0);
}

// ---------------- P1: A2 = [hi(X) | lo(X)]  [4096][2048] bf16 ----------------
__global__ __launch_bounds__(256) void k_split_a2(const float* __restrict__ X,
                                                  unsigned short* __restrict__ A2) {
  const int idx = blockIdx.x * 256 + threadIdx.x;   // float4 index
  const int m = idx >> 8;
  const int c4 = idx & 255;
  const float4 x = ((const float4*)(X + ((size_t)m << 10)))[c4];
  const float xs[4] = {x.x, x.y, x.z, x.w};
  unsigned short hh[4], ll[4];
#pragma unroll
  for (int j = 0; j < 4; ++j) {
    hh[j] = f2bf(xs[j]);
    ll[j] = f2bf(xs[j] - bf2f(hh[j]));
  }
  ushort4* dst = (ushort4*)(A2 + ((size_t)m << 11));
  dst[c4] = make_ushort4(hh[0], hh[1], hh[2], hh[3]);
  dst[c4 + 256] = make_ushort4(ll[0], ll[1], ll[2], ll[3]);
}

// ---------------- P2: W[K][N] -> Bh[N][K]=hi(W)^T, Bl[N][K]=lo(W)^T ----------------
__global__ __launch_bounds__(256) void k_split_b2(const float* __restrict__ W,
                                                  unsigned short* __restrict__ Bh,
                                                  unsigned short* __restrict__ Bl,
                                                  int N, int K) {
  __shared__ unsigned short shi[32][33];
  __shared__ unsigned short slo[32][33];
  const int n0 = blockIdx.x * 32, k0 = blockIdx.y * 32;
  const int ty = threadIdx.x >> 3;   // 0..31
  const int tx = threadIdx.x & 7;    // 0..7
  const float4 w4 = *(const float4*)(W + (size_t)(k0 + ty) * N + n0 + (tx << 2));
  const float wv[4] = {w4.x, w4.y, w4.z, w4.w};
#pragma unroll
  for (int j = 0; j < 4; ++j) {
    const unsigned short hs = f2bf(wv[j]);
    shi[ty][(tx << 2) + j] = hs;
    slo[ty][(tx << 2) + j] = f2bf(wv[j] - bf2f(hs));
  }
  __syncthreads();
  const int n = n0 + ty;
  const ushort4 h = make_ushort4(shi[(tx << 2) + 0][ty], shi[(tx << 2) + 1][ty],
                                 shi[(tx << 2) + 2][ty], shi[(tx << 2) + 3][ty]);
  const ushort4 l = make_ushort4(slo[(tx << 2) + 0][ty], slo[(tx << 2) + 1][ty],
                                 slo[(tx << 2) + 2][ty], slo[(tx << 2) + 3][ty]);
  ((ushort4*)(Bh + (size_t)n * K))[(k0 >> 2) + tx] = h;
  ((ushort4*)(Bl + (size_t)n * K))[(k0 >> 2) + tx] = l;
}

// ---------------- K1: QKV = A2 @ [Bh+Bl]^T + bias -> split-bf16 Q2/K/V ----------------
// 128x128 tile, BK=32, 3-term MFMA: Ah*Bh + Ah*Bl + Al*Bh
__global__ __launch_bounds__(256) void k_qkv3(
    const unsigned short* __restrict__ A, const unsigned short* __restrict__ Bh,
    const unsigned short* __restrict__ Bl, const float* __restrict__ bias,
    unsigned short* __restrict__ Q2, unsigned short* __restrict__ Kht,
    unsigned short* __restrict__ Klt, unsigned short* __restrict__ Vht,
    unsigned short* __restrict__ Vlt) {
  __shared__ unsigned short Ahs[128 * 32], Als[128 * 32], Bhs[128 * 32], Bls[128 * 32];
  const int tid = threadIdx.x, lane = tid & 63, w = tid >> 6;
  const int m0 = blockIdx.y * 128, n0 = blockIdx.x * 128;
  const int wr = (w >> 1) << 6, wc = (w & 1) << 6;
  f32x4 acc[4][4];
#pragma unroll
  for (int i = 0; i < 4; ++i)
#pragma unroll
    for (int j = 0; j < 4; ++j) acc[i][j] = (f32x4){0.f, 0.f, 0.f, 0.f};

  const int lrow = lane >> 2, lk = (lane & 3) << 3;
  const int r0 = (w << 5) + lrow, r1 = r0 + 16;
  const unsigned short* gah0 = A + (size_t)(m0 + r0) * 2048 + lk;
  const unsigned short* gah1 = A + (size_t)(m0 + r1) * 2048 + lk;
  const unsigned short* gbh0 = Bh + (size_t)(n0 + r0) * 1024 + lk;
  const unsigned short* gbh1 = Bh + (size_t)(n0 + r1) * 1024 + lk;
  const unsigned short* gbl0 = Bl + (size_t)(n0 + r0) * 1024 + lk;
  const unsigned short* gbl1 = Bl + (size_t)(n0 + r1) * 1024 + lk;
  unsigned short* lah0 = Ahs + (w << 10) + (lane << 3);
  unsigned short* lal0 = Als + (w << 10) + (lane << 3);
  unsigned short* lbh0 = Bhs + (w << 10) + (lane << 3);
  unsigned short* lbl0 = Bls + (w << 10) + (lane << 3);
  const int fcol = lane & 15, koff = (lane >> 4) << 3;

  for (int k0 = 0; k0 < 1024; k0 += 32) {
    __syncthreads();
    gl_lds16(gah0 + k0, lah0);        gl_lds16(gah1 + k0, lah0 + 512);
    gl_lds16(gah0 + 1024 + k0, lal0); gl_lds16(gah1 + 1024 + k0, lal0 + 512);
    gl_lds16(gbh0 + k0, lbh0);        gl_lds16(gbh1 + k0, lbh0 + 512);
    gl_lds16(gbl0 + k0, lbl0);        gl_lds16(gbl1 + k0, lbl0 + 512);
    __syncthreads();
    bf16x8 afh[4], afl[4], bfh[4], bfl[4];
#pragma unroll
    for (int i = 0; i < 4; ++i) {
      const int off = ((wr + (i << 4) + fcol) << 5) + koff;
      afh[i] = *(const bf16x8*)&Ahs[off];
      afl[i] = *(const bf16x8*)&Als[off];
    }
#pragma unroll
    for (int j = 0; j < 4; ++j) {
      const int off = ((wc + (j << 4) + fcol) << 5) + koff;
      bfh[j] = *(const bf16x8*)&Bhs[off];
      bfl[j] = *(const bf16x8*)&Bls[off];
    }
#pragma unroll
    for (int i = 0; i < 4; ++i)
#pragma unroll
      for (int j = 0; j < 4; ++j) {
        acc[i][j] = __builtin_amdgcn_mfma_f32_16x16x32_bf16(afh[i], bfh[j], acc[i][j], 0, 0, 0);
        acc[i][j] = __builtin_amdgcn_mfma_f32_16x16x32_bf16(afh[i], bfl[j], acc[i][j], 0, 0, 0);
        acc[i][j] = __builtin_amdgcn_mfma_f32_16x16x32_bf16(afl[i], bfh[j], acc[i][j], 0, 0, 0);
      }
  }

  const int qd = lane >> 4;
#pragma unroll
  for (int j = 0; j < 4; ++j) {
    const int n = n0 + wc + (j << 4) + fcol;
    const float bv = bias[n];
    const int which = n >> 10;
    const int c = n & 1023;
    const int hsel = c >> 6, cc = c & 63;
#pragma unroll
    for (int i = 0; i < 4; ++i) {
#pragma unroll
      for (int r = 0; r < 4; ++r) {
        const int m = m0 + wr + (i << 4) + (qd << 2) + r;
        const int b = m >> 10, t = m & 1023;
        const int z = b * NH + hsel;
        const float v = acc[i][j][r] + bv;
        const unsigned short hi = f2bf(v);
        const unsigned short lo = f2bf(v - bf2f(hi));
        if (which == 0) {            // Q2[z][t][128] = [Qh|Ql]
          unsigned short* q = Q2 + (((size_t)z * T_SEQ + t) << 7) + cc;
          q[0] = hi; q[64] = lo;
        } else if (which == 1) {     // Kht/Klt[z][t][64]
          const size_t o = (((size_t)z * T_SEQ + t) << 6) + cc;
          Kht[o] = hi; Klt[o] = lo;
        } else {                     // Vht/Vlt[z][d][1024] (transposed)
          const size_t o = (((size_t)z * HD + cc) << 10) + t;
          Vht[o] = hi; Vlt[o] = lo;
        }
      }
    }
  }
}

// ---------------- K1b: V column suffix sums per (z, segment boundary) ----------------
// SUF[z][s][d] = sum_{k >= 256*(s+1)} V[z][k][d], s = 0..2  (V = Vht+Vlt reconstructed)
__global__ __launch_bounds__(256) void k_vsuf(const unsigned short* __restrict__ Vht,
                                              const unsigned short* __restrict__ Vlt,
                                              float* __restrict__ SUF) {
  const int z = blockIdx.x;
  const int tid = threadIdx.x, lane = tid & 63, w = tid >> 6;
  const unsigned short* vh = Vht + ((size_t)z * HD << 10);
  const unsigned short* vl = Vlt + ((size_t)z * HD << 10);
  for (int d = w; d < 64; d += 4) {
    const unsigned short* rh = vh + ((size_t)d << 10);
    const unsigned short* rl = vl + ((size_t)d << 10);
    float segs[3];
#pragma unroll
    for (int sgi = 0; sgi < 3; ++sgi) {
      const int kb = 256 + (sgi << 8) + (lane << 2);
      const ushort4 h4 = *(const ushort4*)(rh + kb);
      const ushort4 l4 = *(const ushort4*)(rl + kb);
      float acc = bf2f(h4.x) + bf2f(h4.y) + bf2f(h4.z) + bf2f(h4.w)
                + bf2f(l4.x) + bf2f(l4.y) + bf2f(l4.z) + bf2f(l4.w);
      segs[sgi] = wredsum(acc);
    }
    if (lane == 0) {
      float* o = SUF + (size_t)z * 3 * 64;
      o[0 * 64 + d] = segs[0] + segs[1] + segs[2];   // suffix from 256
      o[1 * 64 + d] = segs[1] + segs[2];             // suffix from 512
      o[2 * 64 + d] = segs[2];                       // suffix from 768
    }
  }
}

// ---------------- K2: ATT[z] = (Q2 @ K^T) * 0.125 — CAUSAL tiles only ----------------
// grid (36, 64): blockIdx.x = lower-triangle tile index (n_tile <= m_tile), .y = z
__global__ __launch_bounds__(256) void k_att3(
    const unsigned short* __restrict__ Q2, const unsigned short* __restrict__ Kht,
    const unsigned short* __restrict__ Klt, float* __restrict__ ATT) {
  __shared__ unsigned short Ahs[128 * 32], Als[128 * 32], Bhs[128 * 32], Bls[128 * 32];
  const int tid = threadIdx.x, lane = tid & 63, w = tid >> 6;
  const int z = blockIdx.y;
  // triangular decode: (mt, nt) with nt <= mt
  int ti = blockIdx.x, mt = 0;
  while (ti >= mt + 1) { ti -= mt + 1; ++mt; }
  const int m0 = mt << 7, n0 = ti << 7;

  const unsigned short* A = Q2 + ((size_t)z * T_SEQ << 7);
  const unsigned short* Bh = Kht + ((size_t)z * T_SEQ << 6);
  const unsigned short* Bl = Klt + ((size_t)z * T_SEQ << 6);
  float* Az = ATT + (size_t)z * T_SEQ * T_SEQ;
  const int wr = (w >> 1) << 6, wc = (w & 1) << 6;
  f32x4 acc[4][4];
#pragma unroll
  for (int i = 0; i < 4; ++i)
#pragma unroll
    for (int j = 0; j < 4; ++j) acc[i][j] = (f32x4){0.f, 0.f, 0.f, 0.f};

  const int lrow = lane >> 2, lk = (lane & 3) << 3;
  const int r0 = (w << 5) + lrow, r1 = r0 + 16;
  const unsigned short* gah0 = A + ((size_t)(m0 + r0) << 7) + lk;
  const unsigned short* gah1 = A + ((size_t)(m0 + r1) << 7) + lk;
  const unsigned short* gbh0 = Bh + ((size_t)(n0 + r0) << 6) + lk;
  const unsigned short* gbh1 = Bh + ((size_t)(n0 + r1) << 6) + lk;
  const unsigned short* gbl0 = Bl + ((size_t)(n0 + r0) << 6) + lk;
  const unsigned short* gbl1 = Bl + ((size_t)(n0 + r1) << 6) + lk;
  unsigned short* lah0 = Ahs + (w << 10) + (lane << 3);
  unsigned short* lal0 = Als + (w << 10) + (lane << 3);
  unsigned short* lbh0 = Bhs + (w << 10) + (lane << 3);
  unsigned short* lbl0 = Bls + (w << 10) + (lane << 3);
  const int fcol = lane & 15, koff = (lane >> 4) << 3;

#pragma unroll
  for (int k0 = 0; k0 < 64; k0 += 32) {
    __syncthreads();
    gl_lds16(gah0 + k0, lah0);      gl_lds16(gah1 + k0, lah0 + 512);
    gl_lds16(gah0 + 64 + k0, lal0); gl_lds16(gah1 + 64 + k0, lal0 + 512);
    gl_lds16(gbh0 + k0, lbh0);      gl_lds16(gbh1 + k0, lbh0 + 512);
    gl_lds16(gbl0 + k0, lbl0);      gl_lds16(gbl1 + k0, lbl0 + 512);
    __syncthreads();
    bf16x8 afh[4], afl[4], bfh[4], bfl[4];
#pragma unroll
    for (int i = 0; i < 4; ++i) {
      const int off = ((wr + (i << 4) + fcol) << 5) + koff;
      afh[i] = *(const bf16x8*)&Ahs[off];
      afl[i] = *(const bf16x8*)&Als[off];
    }
#pragma unroll
    for (int j = 0; j < 4; ++j) {
      const int off = ((wc + (j << 4) + fcol) << 5) + koff;
      bfh[j] = *(const bf16x8*)&Bhs[off];
      bfl[j] = *(const bf16x8*)&Bls[off];
    }
#pragma unroll
    for (int i = 0; i < 4; ++i)
#pragma unroll
      for (int j = 0; j < 4; ++j) {
        acc[i][j] = __builtin_amdgcn_mfma_f32_16x16x32_bf16(afh[i], bfh[j], acc[i][j], 0, 0, 0);
        acc[i][j] = __builtin_amdgcn_mfma_f32_16x16x32_bf16(afh[i], bfl[j], acc[i][j], 0, 0, 0);
        acc[i][j] = __builtin_amdgcn_mfma_f32_16x16x32_bf16(afl[i], bfh[j], acc[i][j], 0, 0, 0);
      }
  }

  const int qd = lane >> 4;
#pragma unroll
  for (int i = 0; i < 4; ++i)
#pragma unroll
    for (int r = 0; r < 4; ++r) {
      const int m = wr + (i << 4) + (qd << 2) + r;
#pragma unroll
      for (int j = 0; j < 4; ++j)
        Az[(size_t)(m0 + m) * T_SEQ + (n0 + wc + (j << 4) + fcol)] = acc[i][j][r] * 0.125f;
    }
}

// ---------------- K3: per-row gumbel top-k select + double softmax ----------------
// One wave per row, in-register; writes P IN PLACE as bf16 [Ph|Pl].
// NSEG = number of 256-col segments containing valid (causal) columns for this row.
// Tail columns all equal c_t = exp(-M)/Z: NOT stored; c_t goes to CT[row] for k_pv3.
template<int NSEG>
__device__ __forceinline__ void select_body(
    const float4* __restrict__ arow, const float4* __restrict__ urow,
    ushort4* __restrict__ prow, float* __restrict__ CT, const int row,
    const int t, const int lane, const unsigned k, const float invtemp) {
  constexpr int NE = 4 * NSEG;

  float av[NE], gv[NE];
  unsigned key[NE];
#pragma unroll
  for (int s = 0; s < NSEG; ++s) {
    const float4 a4 = arow[(s << 6) + lane];
    const float4 u4 = urow[(s << 6) + lane];
    const float aa[4] = {a4.x, a4.y, a4.z, a4.w};
    const float uu[4] = {u4.x, u4.y, u4.z, u4.w};
#pragma unroll
    for (int j = 0; j < 4; ++j) {
      const int e = (s << 2) + j;
      const int col = (s << 8) + (lane << 2) + j;
      const float g = -__logf(-__logf(uu[j] + 1e-8f) + 1e-8f);
      av[e] = aa[j];
      gv[e] = (col <= t) ? (aa[j] + g) * invtemp : -INFINITY;
      key[e] = fkey(gv[e]);
    }
  }

  // bitwise binary search for tau = k-th largest key (exact)
  unsigned th = 0u;
#pragma unroll
  for (int b = 31; b >= 0; --b) {
    const unsigned cand = th | (1u << b);
    unsigned c = 0;
#pragma unroll
    for (int e = 0; e < NE; ++e)
      c += (unsigned)__popcll(__ballot(key[e] >= cand));
    if (c >= k) th = cand;
  }
  const unsigned tau = th;

  unsigned cnt_gt = 0;
#pragma unroll
  for (int e = 0; e < NE; ++e)
    cnt_gt += (unsigned)__popcll(__ballot(key[e] > tau));
  const unsigned need = k - cnt_gt;

  const unsigned long long below = ((unsigned long long)1 << lane) - 1ull;
  unsigned rank[NE];
  unsigned base = 0;
#pragma unroll
  for (int s = 0; s < NSEG; ++s) {
    unsigned lanecnt = 0, tot = 0, own = 0;
    unsigned long long B[4];
#pragma unroll
    for (int j = 0; j < 4; ++j) {
      B[j] = __ballot(key[(s << 2) + j] == tau);
      lanecnt += (unsigned)__popcll(B[j] & below);
      tot += (unsigned)__popcll(B[j]);
    }
#pragma unroll
    for (int j = 0; j < 4; ++j) {
      rank[(s << 2) + j] = base + lanecnt + own;
      own += (key[(s << 2) + j] == tau) ? 1u : 0u;
    }
    base += tot;
  }

  bool sel[NE];
#pragma unroll
  for (int e = 0; e < NE; ++e)
    sel[e] = (key[e] > tau) | ((key[e] == tau) & (rank[e] < need));

  float lm = -INFINITY;
#pragma unroll
  for (int e = 0; e < NE; ++e) lm = fmaxf(lm, gv[e]);
  const float m = wredmax(lm);

  float ex[NE];
  float ps = 0.f;
#pragma unroll
  for (int e = 0; e < NE; ++e) {
    ex[e] = sel[e] ? __expf(gv[e] - m) : 0.f;
    ps += ex[e];
  }
  const float S = wredsum(ps);
  const float invS = 1.f / S;

  float sp[NE];
#pragma unroll
  for (int e = 0; e < NE; ++e) sp[e] = sel[e] ? av[e] * ex[e] * invS : 0.f;

  // final softmax over the FULL 1024-wide row; tail cols have sp == 0
  float lM = 0.f;
#pragma unroll
  for (int e = 0; e < NE; ++e) lM = fmaxf(lM, sp[e]);
  const float M = wredmax(lM);

  float pe[NE];
  float lz = 0.f;
#pragma unroll
  for (int e = 0; e < NE; ++e) { pe[e] = __expf(sp[e] - M); lz += pe[e]; }
  const float ez = __expf(0.f - M);                 // value at every tail column
  const float Z = wredsum(lz) + (float)(1024 - 256 * NSEG) * ez;
  const float invZ = 1.f / Z;

  // write split-bf16 [Ph|Pl] in place — only the first NSEG segments
#pragma unroll
  for (int s = 0; s < NSEG; ++s) {
    unsigned short hh[4], ll[4];
#pragma unroll
    for (int j = 0; j < 4; ++j) {
      const float p = pe[(s << 2) + j] * invZ;
      hh[j] = f2bf(p);
      ll[j] = f2bf(p - bf2f(hh[j]));
    }
    prow[(s << 6) + lane] = make_ushort4(hh[0], hh[1], hh[2], hh[3]);
    prow[256 + (s << 6) + lane] = make_ushort4(ll[0], ll[1], ll[2], ll[3]);
  }
  if (NSEG < 4) {
    if (lane == 0) CT[row] = ez * invZ;   // constant tail value for k_pv3
  }
}

__global__ __launch_bounds__(256, 4) void k_select(
    const float* __restrict__ ATT, unsigned short* __restrict__ P2,
    const float* __restrict__ NOISE, float* __restrict__ CT,
    const float* __restrict__ SR, const float* __restrict__ GT) {
  const int tid = threadIdx.x;
  const int lane = tid & 63;
  const int row = (blockIdx.x << 2) | (tid >> 6);   // t is wave-uniform
  const int t = row & 1023;
  const int h = (row >> 10) & 15;

  const float ratio = 1.f / (1.f + __expf(-SR[h]));
  const float temp = log1pf(__expf(GT[h])) + 0.1f;
  const float invtemp = 1.f / temp;
  const int kf = (int)floorf((float)(t + 1) * ratio);
  const unsigned k = (unsigned)(kf < 1 ? 1 : kf);

  const float4* arow = (const float4*)(ATT + ((size_t)row << 10));
  const float4* urow = (const float4*)(NOISE + ((size_t)row << 10));
  ushort4* prow = (ushort4*)(P2 + ((size_t)row << 11));

  switch (t >> 8) {   // wave-uniform branch
    case 0:  select_body<1>(arow, urow, prow, CT, row, t, lane, k, invtemp); break;
    case 1:  select_body<2>(arow, urow, prow, CT, row, t, lane, k, invtemp); break;
    case 2:  select_body<3>(arow, urow, prow, CT, row, t, lane, k, invtemp); break;
    default: select_body<4>(arow, urow, prow, CT, row, t, lane, k, invtemp); break;
  }
}

// ---------------- K4: Y2 = P2 @ V, K shortened to 256*NSEG + rank-1 tail fix ----------
__global__ __launch_bounds__(256) void k_pv3(
    const unsigned short* __restrict__ P2, const unsigned short* __restrict__ Vht,
    const unsigned short* __restrict__ Vlt, const float* __restrict__ CT,
    const float* __restrict__ SUF, unsigned short* __restrict__ Y2) {
  __shared__ unsigned short Ahs[128 * 32], Als[128 * 32], Bhs[64 * 32], Bls[64 * 32];
  const int tid = threadIdx.x, lane = tid & 63, w = tid >> 6;
  const int z = blockIdx.z;
  const int b = z >> 4, h = z & 15;
  const unsigned short* A = P2 + ((size_t)z * T_SEQ << 11);
  const unsigned short* Bh = Vht + ((size_t)z * HD << 10);
  const unsigned short* Bl = Vlt + ((size_t)z * HD << 10);
  const int m0 = blockIdx.x * 128;
  // 128-row tile lies within a single 256-col NSEG class:
  const int NSEG = (int)(blockIdx.x >> 1) + 1;      // 1..4
  const int KLEN = NSEG << 8;                       // 256*NSEG
  const int wr = (w >> 1) << 6, wc = (w & 1) << 5;
  f32x4 acc[4][2];
#pragma unroll
  for (int i = 0; i < 4; ++i)
#pragma unroll
    for (int j = 0; j < 2; ++j) acc[i][j] = (f32x4){0.f, 0.f, 0.f, 0.f};

  const int lrow = lane >> 2, lk = (lane & 3) << 3;
  const int ra0 = (w << 5) + lrow, ra1 = ra0 + 16;
  const int rb = (w << 4) + lrow;
  const unsigned short* gah0 = A + ((size_t)(m0 + ra0) << 11) + lk;
  const unsigned short* gah1 = A + ((size_t)(m0 + ra1) << 11) + lk;
  const unsigned short* gbh = Bh + ((size_t)rb << 10) + lk;
  const unsigned short* gbl = Bl + ((size_t)rb << 10) + lk;
  unsigned short* lah0 = Ahs + (w << 10) + (lane << 3);
  unsigned short* lal0 = Als + (w << 10) + (lane << 3);
  unsigned short* lbh = Bhs + (w << 9) + (lane << 3);
  unsigned short* lbl = Bls + (w << 9) + (lane << 3);
  const int fcol = lane & 15, koff = (lane >> 4) << 3;

  for (int k0 = 0; k0 < KLEN; k0 += 32) {
    __syncthreads();
    gl_lds16(gah0 + k0, lah0);        gl_lds16(gah1 + k0, lah0 + 512);
    gl_lds16(gah0 + 1024 + k0, lal0); gl_lds16(gah1 + 1024 + k0, lal0 + 512);
    gl_lds16(gbh + k0, lbh);
    gl_lds16(gbl + k0, lbl);
    __syncthreads();
    bf16x8 afh[4], afl[4], bfh[2], bfl[2];
#pragma unroll
    for (int i = 0; i < 4; ++i) {
      const int off = ((wr + (i << 4) + fcol) << 5) + koff;
      afh[i] = *(const bf16x8*)&Ahs[off];
      afl[i] = *(const bf16x8*)&Als[off];
    }
#pragma unroll
    for (int j = 0; j < 2; ++j) {
      const int off = ((wc + (j << 4) + fcol) << 5) + koff;
      bfh[j] = *(const bf16x8*)&Bhs[off];
      bfl[j] = *(const bf16x8*)&Bls[off];
    }
#pragma unroll
    for (int i = 0; i < 4; ++i)
#pragma unroll
      for (int j = 0; j < 2; ++j) {
        acc[i][j] = __builtin_amdgcn_mfma_f32_16x16x32_bf16(afh[i], bfh[j], acc[i][j], 0, 0, 0);
        acc[i][j] = __builtin_amdgcn_mfma_f32_16x16x32_bf16(afh[i], bfl[j], acc[i][j], 0, 0, 0);
        acc[i][j] = __builtin_amdgcn_mfma_f32_16x16x32_bf16(afl[i], bfh[j], acc[i][j], 0, 0, 0);
      }
  }

  const int qd = lane >> 4;
  // constant-tail correction: Y[t,d] += CT[t] * SUF[z][NSEG-1][d]
  float ct[4][4];
  if (NSEG < 4) {
    const float* ctp = CT + ((size_t)z << 10) + m0;
#pragma unroll
    for (int i = 0; i < 4; ++i)
#pragma unroll
      for (int r = 0; r < 4; ++r)
        ct[i][r] = ctp[wr + (i << 4) + (qd << 2) + r];
  }
#pragma unroll
  for (int j = 0; j < 2; ++j) {
    const int d = wc + (j << 4) + fcol;      // 0..63
    const int c = (h << 6) + d;              // col in Y
    float sv = 0.f;
    if (NSEG < 4) sv = SUF[((size_t)z * 3 + (NSEG - 1)) * 64 + d];
#pragma unroll
    for (int i = 0; i < 4; ++i) {
#pragma unroll
      for (int r = 0; r < 4; ++r) {
        const int tq = m0 + wr + (i << 4) + (qd << 2) + r;
        float v = acc[i][j][r];
        if (NSEG < 4) v += ct[i][r] * sv;
        const unsigned short hi = f2bf(v);
        const unsigned short lo = f2bf(v - bf2f(hi));
        unsigned short* y = Y2 + (((size_t)(b * T_SEQ + tq)) << 11) + c;
        y[0] = hi; y[1024] = lo;
      }
    }
  }
}

// ---------------- K5: OUT = Y2 @ [Wph+Wpl]^T + b_proj ----------------
__global__ __launch_bounds__(256) void k_proj3(
    const unsigned short* __restrict__ A, const unsigned short* __restrict__ Bh,
    const unsigned short* __restrict__ Bl, const float* __restrict__ bias,
    float* __restrict__ OUT) {
  __shared__ unsigned short Ahs[128 * 32], Als[128 * 32], Bhs[128 * 32], Bls[128 * 32];
  const int tid = threadIdx.x, lane = tid & 63, w = tid >> 6;
  const int m0 = blockIdx.y * 128, n0 = blockIdx.x * 128;
  const int wr = (w >> 1) << 6, wc = (w & 1) << 6;
  f32x4 acc[4][4];
#pragma unroll
  for (int i = 0; i < 4; ++i)
#pragma unroll
    for (int j = 0; j < 4; ++j) acc[i][j] = (f32x4){0.f, 0.f, 0.f, 0.f};

  const int lrow = lane >> 2, lk = (lane & 3) << 3;
  const int r0 = (w << 5) + lrow, r1 = r0 + 16;
  const unsigned short* gah0 = A + ((size_t)(m0 + r0) << 11) + lk;
  const unsigned short* gah1 = A + ((size_t)(m0 + r1) << 11) + lk;
  const unsigned short* gbh0 = Bh + ((size_t)(n0 + r0) << 10) + lk;
  const unsigned short* gbh1 = Bh + ((size_t)(n0 + r1) << 10) + lk;
  const unsigned short* gbl0 = Bl + ((size_t)(n0 + r0) << 10) + lk;
  const unsigned short* gbl1 = Bl + ((size_t)(n0 + r1) << 10) + lk;
  unsigned short* lah0 = Ahs + (w << 10) + (lane << 3);
  unsigned short* lal0 = Als + (w << 10) + (lane << 3);
  unsigned short* lbh0 = Bhs + (w << 10) + (lane << 3);
  unsigned short* lbl0 = Bls + (w << 10) + (lane << 3);
  const int fcol = lane & 15, koff = (lane >> 4) << 3;

  for (int k0 = 0; k0 < 1024; k0 += 32) {
    __syncthreads();
    gl_lds16(gah0 + k0, lah0);        gl_lds16(gah1 + k0, lah0 + 512);
    gl_lds16(gah0 + 1024 + k0, lal0); gl_lds16(gah1 + 1024 + k0, lal0 + 512);
    gl_lds16(gbh0 + k0, lbh0);        gl_lds16(gbh1 + k0, lbh0 + 512);
    gl_lds16(gbl0 + k0, lbl0);        gl_lds16(gbl1 + k0, lbl0 + 512);
    __syncthreads();
    bf16x8 afh[4], afl[4], bfh[4], bfl[4];
#pragma unroll
    for (int i = 0; i < 4; ++i) {
      const int off = ((wr + (i << 4) + fcol) << 5) + koff;
      afh[i] = *(const bf16x8*)&Ahs[off];
      afl[i] = *(const bf16x8*)&Als[off];
    }
#pragma unroll
    for (int j = 0; j < 4; ++j) {
      const int off = ((wc + (j << 4) + fcol) << 5) + koff;
      bfh[j] = *(const bf16x8*)&Bhs[off];
      bfl[j] = *(const bf16x8*)&Bls[off];
    }
#pragma unroll
    for (int i = 0; i < 4; ++i)
#pragma unroll
      for (int j = 0; j < 4; ++j) {
        acc[i][j] = __builtin_amdgcn_mfma_f32_16x16x32_bf16(afh[i], bfh[j], acc[i][j], 0, 0, 0);
        acc[i][j] = __builtin_amdgcn_mfma_f32_16x16x32_bf16(afh[i], bfl[j], acc[i][j], 0, 0, 0);
        acc[i][j] = __builtin_amdgcn_mfma_f32_16x16x32_bf16(afl[i], bfh[j], acc[i][j], 0, 0, 0);
      }
  }

  const int qd = lane >> 4;
#pragma unroll
  for (int j = 0; j < 4; ++j) {
    const int n = n0 + wc + (j << 4) + fcol;
    const float bv = bias[n];
#pragma unroll
    for (int i = 0; i < 4; ++i)
#pragma unroll
      for (int r = 0; r < 4; ++r) {
        const int m = m0 + wr + (i << 4) + (qd << 2) + r;
        OUT[((size_t)m << 10) + n] = acc[i][j][r] + bv;
      }
  }
}

extern "C" void kernel_launch(void* const* d_in, const int* in_sizes, int n_in,
                              void* d_out, int out_size, void* d_ws, size_t ws_size,
                              hipStream_t stream) {
  const float* x      = (const float*)d_in[0];
  const float* W_attn = (const float*)d_in[1];
  const float* b_attn = (const float*)d_in[2];
  const float* W_proj = (const float*)d_in[3];
  const float* b_proj = (const float*)d_in[4];
  const float* sr     = (const float*)d_in[5];
  const float* gt     = (const float*)d_in[6];
  const float* noise  = (const float*)d_in[7];

  char* base = (char*)d_ws;
  // [0, 268435456): ATT fp32 (later overwritten in-place by P2 bf16).
  //   Prep aliases inside (dead after k_qkv3): A2q, Bhq, Blq.
  float*          ATT = (float*)base;
  unsigned short* A2q = (unsigned short*)base;                    // 16 MB
  unsigned short* Bhq = (unsigned short*)(base + 16777216);       //  6 MB
  unsigned short* Blq = (unsigned short*)(base + 23068672);       //  6 MB
  unsigned short* P2  = (unsigned short*)base;                    // in-place over ATT
  // [268435456, +16 MB): Q2; after k_att3 reused for W_proj split
  unsigned short* Q2  = (unsigned short*)(base + 268435456);
  unsigned short* Wph = (unsigned short*)(base + 268435456);
  unsigned short* Wpl = (unsigned short*)(base + 270532608);
  // [285212672, +16 MB): Kht+Klt; after k_att3 reused for Y2
  unsigned short* Kht = (unsigned short*)(base + 285212672);
  unsigned short* Klt = (unsigned short*)(base + 293601280);
  unsigned short* Y2  = (unsigned short*)(base + 285212672);
  // [301989888, +16 MB): Vht+Vlt
  unsigned short* Vht = (unsigned short*)(base + 301989888);
  unsigned short* Vlt = (unsigned short*)(base + 310378496);
  // [318767104, +256 KB): CT per-row tail constant; then SUF [64][3][64] f32
  float* CT  = (float*)(base + 318767104);
  float* SUF = (float*)(base + 319029248);
  float* OUT = (float*)d_out;

  k_split_a2<<<dim3(4096),     256, 0, stream>>>(x, A2q);
  k_split_b2<<<dim3(96, 32),   256, 0, stream>>>(W_attn, Bhq, Blq, 3072, 1024);
  k_qkv3    <<<dim3(24, 32),   256, 0, stream>>>(A2q, Bhq, Blq, b_attn, Q2, Kht, Klt, Vht, Vlt);
  k_vsuf    <<<dim3(64),       256, 0, stream>>>(Vht, Vlt, SUF);
  k_att3    <<<dim3(36, 64),   256, 0, stream>>>(Q2, Kht, Klt, ATT);
  k_split_b2<<<dim3(32, 32),   256, 0, stream>>>(W_proj, Wph, Wpl, 1024, 1024);
  k_select  <<<dim3(16384),    256, 0, stream>>>(ATT, P2, noise, CT, sr, gt);
  k_pv3     <<<dim3(8, 1, 64), 256, 0, stream>>>(P2, Vht, Vlt, CT, SUF, Y2);
  k_proj3   <<<dim3(8, 32),    256, 0, stream>>>(Y2, Wph, Wpl, b_proj, OUT);
}

// Round 3
// 767.117 us; speedup vs baseline: 1.0633x; 1.0633x over previous
//
#include <hip/hip_runtime.h>
#include <math.h>

#define T_SEQ 1024
#define NH 16
#define HD 64

typedef __attribute__((ext_vector_type(8))) short bf16x8;
typedef __attribute__((ext_vector_type(4))) float f32x4;

// monotone float -> uint key: a<b (float) <=> fkey(a)<fkey(b) (uint)
__device__ __forceinline__ unsigned fkey(float x) {
  unsigned u = __float_as_uint(x);
  return (u & 0x80000000u) ? ~u : (u | 0x80000000u);
}

__device__ __forceinline__ float wredmax(float v) {
#pragma unroll
  for (int m = 1; m < 64; m <<= 1) v = fmaxf(v, __shfl_xor(v, m));
  return v;
}
__device__ __forceinline__ float wredsum(float v) {
#pragma unroll
  for (int m = 1; m < 64; m <<= 1) v += __shfl_xor(v, m);
  return v;
}

// fp32 -> bf16 round-to-nearest-even (finite inputs)
__device__ __forceinline__ unsigned short f2bf(float f) {
  unsigned u = __float_as_uint(f);
  return (unsigned short)((u + 0x7fffu + ((u >> 16) & 1u)) >> 16);
}
__device__ __forceinline__ float bf2f(unsigned short h) {
  return __uint_as_float(((unsigned)h) << 16);
}

// async global->LDS, 16B/lane (LDS dest = wave-uniform base + lane*16)
__device__ __forceinline__ void gl_lds16(const void* g, void* l) {
  __builtin_amdgcn_global_load_lds(
      (const __attribute__((address_space(1))) unsigned int*)g,
      (__attribute__((address_space(3))) unsigned int*)l,
      16, 0, 0);
}

// ---------------- P1: A2 = [hi(X) | lo(X)]  [4096][2048] bf16 ----------------
__global__ __launch_bounds__(256) void k_split_a2(const float* __restrict__ X,
                                                  unsigned short* __restrict__ A2) {
  const int idx = blockIdx.x * 256 + threadIdx.x;   // float4 index
  const int m = idx >> 8;
  const int c4 = idx & 255;
  const float4 x = ((const float4*)(X + ((size_t)m << 10)))[c4];
  const float xs[4] = {x.x, x.y, x.z, x.w};
  unsigned short hh[4], ll[4];
#pragma unroll
  for (int j = 0; j < 4; ++j) {
    hh[j] = f2bf(xs[j]);
    ll[j] = f2bf(xs[j] - bf2f(hh[j]));
  }
  ushort4* dst = (ushort4*)(A2 + ((size_t)m << 11));
  dst[c4] = make_ushort4(hh[0], hh[1], hh[2], hh[3]);
  dst[c4 + 256] = make_ushort4(ll[0], ll[1], ll[2], ll[3]);
}

// ---------------- P2: W[K][N] -> Bh[N][K]=hi(W)^T, Bl[N][K]=lo(W)^T ----------------
__global__ __launch_bounds__(256) void k_split_b2(const float* __restrict__ W,
                                                  unsigned short* __restrict__ Bh,
                                                  unsigned short* __restrict__ Bl,
                                                  int N, int K) {
  __shared__ unsigned short shi[32][33];
  __shared__ unsigned short slo[32][33];
  const int n0 = blockIdx.x * 32, k0 = blockIdx.y * 32;
  const int ty = threadIdx.x >> 3;   // 0..31
  const int tx = threadIdx.x & 7;    // 0..7
  const float4 w4 = *(const float4*)(W + (size_t)(k0 + ty) * N + n0 + (tx << 2));
  const float wv[4] = {w4.x, w4.y, w4.z, w4.w};
#pragma unroll
  for (int j = 0; j < 4; ++j) {
    const unsigned short hs = f2bf(wv[j]);
    shi[ty][(tx << 2) + j] = hs;
    slo[ty][(tx << 2) + j] = f2bf(wv[j] - bf2f(hs));
  }
  __syncthreads();
  const int n = n0 + ty;
  const ushort4 h = make_ushort4(shi[(tx << 2) + 0][ty], shi[(tx << 2) + 1][ty],
                                 shi[(tx << 2) + 2][ty], shi[(tx << 2) + 3][ty]);
  const ushort4 l = make_ushort4(slo[(tx << 2) + 0][ty], slo[(tx << 2) + 1][ty],
                                 slo[(tx << 2) + 2][ty], slo[(tx << 2) + 3][ty]);
  ((ushort4*)(Bh + (size_t)n * K))[(k0 >> 2) + tx] = h;
  ((ushort4*)(Bl + (size_t)n * K))[(k0 >> 2) + tx] = l;
}

// ---------------- K1: QKV = A2 @ [Bh+Bl]^T + bias -> split-bf16 Q2/K/V ----------------
// 128x128 tile, BK=32, 3-term MFMA, 2-phase double-buffered LDS pipeline.
__global__ __launch_bounds__(256) void k_qkv3(
    const unsigned short* __restrict__ A, const unsigned short* __restrict__ Bh,
    const unsigned short* __restrict__ Bl, const float* __restrict__ bias,
    unsigned short* __restrict__ Q2, unsigned short* __restrict__ Kht,
    unsigned short* __restrict__ Klt, unsigned short* __restrict__ Vht,
    unsigned short* __restrict__ Vlt) {
  __shared__ unsigned short Ahs[2][128 * 32], Als[2][128 * 32],
                            Bhs[2][128 * 32], Bls[2][128 * 32];
  const int tid = threadIdx.x, lane = tid & 63, w = tid >> 6;
  const int m0 = blockIdx.y * 128, n0 = blockIdx.x * 128;
  const int wr = (w >> 1) << 6, wc = (w & 1) << 6;
  f32x4 acc[4][4];
#pragma unroll
  for (int i = 0; i < 4; ++i)
#pragma unroll
    for (int j = 0; j < 4; ++j) acc[i][j] = (f32x4){0.f, 0.f, 0.f, 0.f};

  const int lrow = lane >> 2, lk = (lane & 3) << 3;
  const int r0 = (w << 5) + lrow, r1 = r0 + 16;
  const unsigned short* gah0 = A + (size_t)(m0 + r0) * 2048 + lk;
  const unsigned short* gah1 = A + (size_t)(m0 + r1) * 2048 + lk;
  const unsigned short* gbh0 = Bh + (size_t)(n0 + r0) * 1024 + lk;
  const unsigned short* gbh1 = Bh + (size_t)(n0 + r1) * 1024 + lk;
  const unsigned short* gbl0 = Bl + (size_t)(n0 + r0) * 1024 + lk;
  const unsigned short* gbl1 = Bl + (size_t)(n0 + r1) * 1024 + lk;
  const int stoff = (w << 10) + (lane << 3);
  const int fcol = lane & 15, koff = (lane >> 4) << 3;

  auto STAGE = [&](int buf, int k0) {
    gl_lds16(gah0 + k0, Ahs[buf] + stoff);        gl_lds16(gah1 + k0, Ahs[buf] + stoff + 512);
    gl_lds16(gah0 + 1024 + k0, Als[buf] + stoff); gl_lds16(gah1 + 1024 + k0, Als[buf] + stoff + 512);
    gl_lds16(gbh0 + k0, Bhs[buf] + stoff);        gl_lds16(gbh1 + k0, Bhs[buf] + stoff + 512);
    gl_lds16(gbl0 + k0, Bls[buf] + stoff);        gl_lds16(gbl1 + k0, Bls[buf] + stoff + 512);
  };
  auto COMPUTE = [&](int buf) {
    bf16x8 afh[4], afl[4], bfh[4], bfl[4];
#pragma unroll
    for (int i = 0; i < 4; ++i) {
      const int off = ((wr + (i << 4) + fcol) << 5) + koff;
      afh[i] = *(const bf16x8*)&Ahs[buf][off];
      afl[i] = *(const bf16x8*)&Als[buf][off];
    }
#pragma unroll
    for (int j = 0; j < 4; ++j) {
      const int off = ((wc + (j << 4) + fcol) << 5) + koff;
      bfh[j] = *(const bf16x8*)&Bhs[buf][off];
      bfl[j] = *(const bf16x8*)&Bls[buf][off];
    }
#pragma unroll
    for (int i = 0; i < 4; ++i)
#pragma unroll
      for (int j = 0; j < 4; ++j) {
        acc[i][j] = __builtin_amdgcn_mfma_f32_16x16x32_bf16(afh[i], bfh[j], acc[i][j], 0, 0, 0);
        acc[i][j] = __builtin_amdgcn_mfma_f32_16x16x32_bf16(afh[i], bfl[j], acc[i][j], 0, 0, 0);
        acc[i][j] = __builtin_amdgcn_mfma_f32_16x16x32_bf16(afl[i], bfh[j], acc[i][j], 0, 0, 0);
      }
  };

  STAGE(0, 0);
  __syncthreads();
  int cur = 0;
  for (int t = 0; t < 31; ++t) {
    STAGE(cur ^ 1, (t + 1) << 5);   // issue next-tile loads BEFORE compute
    COMPUTE(cur);
    __syncthreads();                // vmcnt(0)+lgkmcnt(0)+barrier: next tile ready
    cur ^= 1;
  }
  COMPUTE(cur);

  const int qd = lane >> 4;
#pragma unroll
  for (int j = 0; j < 4; ++j) {
    const int n = n0 + wc + (j << 4) + fcol;
    const float bv = bias[n];
    const int which = n >> 10;
    const int c = n & 1023;
    const int hsel = c >> 6, cc = c & 63;
#pragma unroll
    for (int i = 0; i < 4; ++i) {
#pragma unroll
      for (int r = 0; r < 4; ++r) {
        const int m = m0 + wr + (i << 4) + (qd << 2) + r;
        const int b = m >> 10, t = m & 1023;
        const int z = b * NH + hsel;
        const float v = acc[i][j][r] + bv;
        const unsigned short hi = f2bf(v);
        const unsigned short lo = f2bf(v - bf2f(hi));
        if (which == 0) {            // Q2[z][t][128] = [Qh|Ql]
          unsigned short* q = Q2 + (((size_t)z * T_SEQ + t) << 7) + cc;
          q[0] = hi; q[64] = lo;
        } else if (which == 1) {     // Kht/Klt[z][t][64]
          const size_t o = (((size_t)z * T_SEQ + t) << 6) + cc;
          Kht[o] = hi; Klt[o] = lo;
        } else {                     // Vht/Vlt[z][d][1024] (transposed)
          const size_t o = (((size_t)z * HD + cc) << 10) + t;
          Vht[o] = hi; Vlt[o] = lo;
        }
      }
    }
  }
}

// ---------------- K1b: V column suffix sums per (z, segment boundary) ----------------
// SUF[z][s][d] = sum_{k >= 256*(s+1)} V[z][k][d], s = 0..2  (V = Vht+Vlt reconstructed)
__global__ __launch_bounds__(256) void k_vsuf(const unsigned short* __restrict__ Vht,
                                              const unsigned short* __restrict__ Vlt,
                                              float* __restrict__ SUF) {
  const int z = blockIdx.x;
  const int tid = threadIdx.x, lane = tid & 63, w = tid >> 6;
  const unsigned short* vh = Vht + ((size_t)z * HD << 10);
  const unsigned short* vl = Vlt + ((size_t)z * HD << 10);
  for (int d = w; d < 64; d += 4) {
    const unsigned short* rh = vh + ((size_t)d << 10);
    const unsigned short* rl = vl + ((size_t)d << 10);
    float segs[3];
#pragma unroll
    for (int sgi = 0; sgi < 3; ++sgi) {
      const int kb = 256 + (sgi << 8) + (lane << 2);
      const ushort4 h4 = *(const ushort4*)(rh + kb);
      const ushort4 l4 = *(const ushort4*)(rl + kb);
      float acc = bf2f(h4.x) + bf2f(h4.y) + bf2f(h4.z) + bf2f(h4.w)
                + bf2f(l4.x) + bf2f(l4.y) + bf2f(l4.z) + bf2f(l4.w);
      segs[sgi] = wredsum(acc);
    }
    if (lane == 0) {
      float* o = SUF + (size_t)z * 3 * 64;
      o[0 * 64 + d] = segs[0] + segs[1] + segs[2];   // suffix from 256
      o[1 * 64 + d] = segs[1] + segs[2];             // suffix from 512
      o[2 * 64 + d] = segs[2];                       // suffix from 768
    }
  }
}

// ---------------- K2: ATT[z] = (Q2 @ K^T) * 0.125 — CAUSAL tiles only ----------------
// grid (36, 64): blockIdx.x = lower-triangle tile index (n_tile <= m_tile), .y = z
__global__ __launch_bounds__(256) void k_att3(
    const unsigned short* __restrict__ Q2, const unsigned short* __restrict__ Kht,
    const unsigned short* __restrict__ Klt, float* __restrict__ ATT) {
  __shared__ unsigned short Ahs[128 * 32], Als[128 * 32], Bhs[128 * 32], Bls[128 * 32];
  const int tid = threadIdx.x, lane = tid & 63, w = tid >> 6;
  const int z = blockIdx.y;
  // triangular decode: (mt, nt) with nt <= mt
  int ti = blockIdx.x, mt = 0;
  while (ti >= mt + 1) { ti -= mt + 1; ++mt; }
  const int m0 = mt << 7, n0 = ti << 7;

  const unsigned short* A = Q2 + ((size_t)z * T_SEQ << 7);
  const unsigned short* Bh = Kht + ((size_t)z * T_SEQ << 6);
  const unsigned short* Bl = Klt + ((size_t)z * T_SEQ << 6);
  float* Az = ATT + (size_t)z * T_SEQ * T_SEQ;
  const int wr = (w >> 1) << 6, wc = (w & 1) << 6;
  f32x4 acc[4][4];
#pragma unroll
  for (int i = 0; i < 4; ++i)
#pragma unroll
    for (int j = 0; j < 4; ++j) acc[i][j] = (f32x4){0.f, 0.f, 0.f, 0.f};

  const int lrow = lane >> 2, lk = (lane & 3) << 3;
  const int r0 = (w << 5) + lrow, r1 = r0 + 16;
  const unsigned short* gah0 = A + ((size_t)(m0 + r0) << 7) + lk;
  const unsigned short* gah1 = A + ((size_t)(m0 + r1) << 7) + lk;
  const unsigned short* gbh0 = Bh + ((size_t)(n0 + r0) << 6) + lk;
  const unsigned short* gbh1 = Bh + ((size_t)(n0 + r1) << 6) + lk;
  const unsigned short* gbl0 = Bl + ((size_t)(n0 + r0) << 6) + lk;
  const unsigned short* gbl1 = Bl + ((size_t)(n0 + r1) << 6) + lk;
  unsigned short* lah0 = Ahs + (w << 10) + (lane << 3);
  unsigned short* lal0 = Als + (w << 10) + (lane << 3);
  unsigned short* lbh0 = Bhs + (w << 10) + (lane << 3);
  unsigned short* lbl0 = Bls + (w << 10) + (lane << 3);
  const int fcol = lane & 15, koff = (lane >> 4) << 3;

#pragma unroll
  for (int k0 = 0; k0 < 64; k0 += 32) {
    __syncthreads();
    gl_lds16(gah0 + k0, lah0);      gl_lds16(gah1 + k0, lah0 + 512);
    gl_lds16(gah0 + 64 + k0, lal0); gl_lds16(gah1 + 64 + k0, lal0 + 512);
    gl_lds16(gbh0 + k0, lbh0);      gl_lds16(gbh1 + k0, lbh0 + 512);
    gl_lds16(gbl0 + k0, lbl0);      gl_lds16(gbl1 + k0, lbl0 + 512);
    __syncthreads();
    bf16x8 afh[4], afl[4], bfh[4], bfl[4];
#pragma unroll
    for (int i = 0; i < 4; ++i) {
      const int off = ((wr + (i << 4) + fcol) << 5) + koff;
      afh[i] = *(const bf16x8*)&Ahs[off];
      afl[i] = *(const bf16x8*)&Als[off];
    }
#pragma unroll
    for (int j = 0; j < 4; ++j) {
      const int off = ((wc + (j << 4) + fcol) << 5) + koff;
      bfh[j] = *(const bf16x8*)&Bhs[off];
      bfl[j] = *(const bf16x8*)&Bls[off];
    }
#pragma unroll
    for (int i = 0; i < 4; ++i)
#pragma unroll
      for (int j = 0; j < 4; ++j) {
        acc[i][j] = __builtin_amdgcn_mfma_f32_16x16x32_bf16(afh[i], bfh[j], acc[i][j], 0, 0, 0);
        acc[i][j] = __builtin_amdgcn_mfma_f32_16x16x32_bf16(afh[i], bfl[j], acc[i][j], 0, 0, 0);
        acc[i][j] = __builtin_amdgcn_mfma_f32_16x16x32_bf16(afl[i], bfh[j], acc[i][j], 0, 0, 0);
      }
  }

  const int qd = lane >> 4;
#pragma unroll
  for (int i = 0; i < 4; ++i)
#pragma unroll
    for (int r = 0; r < 4; ++r) {
      const int m = wr + (i << 4) + (qd << 2) + r;
#pragma unroll
      for (int j = 0; j < 4; ++j)
        Az[(size_t)(m0 + m) * T_SEQ + (n0 + wc + (j << 4) + fcol)] = acc[i][j][r] * 0.125f;
    }
}

// ---------------- K3: per-row gumbel top-k select + double softmax ----------------
// One wave per row, in-register; writes P IN PLACE as bf16 [Ph|Pl].
// NSEG = number of 256-col segments containing valid (causal) columns for this row.
// Tail columns all equal c_t = exp(-M)/Z: NOT stored; c_t goes to CT[row] for k_pv3.
template<int NSEG>
__device__ __forceinline__ void select_body(
    const float4* __restrict__ arow, const float4* __restrict__ urow,
    ushort4* __restrict__ prow, float* __restrict__ CT, const int row,
    const int t, const int lane, const unsigned k, const float invtemp) {
  constexpr int NE = 4 * NSEG;

  float av[NE], gv[NE];
  unsigned key[NE];
#pragma unroll
  for (int s = 0; s < NSEG; ++s) {
    const float4 a4 = arow[(s << 6) + lane];
    const float4 u4 = urow[(s << 6) + lane];
    const float aa[4] = {a4.x, a4.y, a4.z, a4.w};
    const float uu[4] = {u4.x, u4.y, u4.z, u4.w};
#pragma unroll
    for (int j = 0; j < 4; ++j) {
      const int e = (s << 2) + j;
      const int col = (s << 8) + (lane << 2) + j;
      const float g = -__logf(-__logf(uu[j] + 1e-8f) + 1e-8f);
      av[e] = aa[j];
      gv[e] = (col <= t) ? (aa[j] + g) * invtemp : -INFINITY;
      key[e] = fkey(gv[e]);
    }
  }

  // bitwise binary search for tau = k-th largest key (exact)
  unsigned th = 0u;
#pragma unroll
  for (int b = 31; b >= 0; --b) {
    const unsigned cand = th | (1u << b);
    unsigned c = 0;
#pragma unroll
    for (int e = 0; e < NE; ++e)
      c += (unsigned)__popcll(__ballot(key[e] >= cand));
    if (c >= k) th = cand;
  }
  const unsigned tau = th;

  unsigned cnt_gt = 0;
#pragma unroll
  for (int e = 0; e < NE; ++e)
    cnt_gt += (unsigned)__popcll(__ballot(key[e] > tau));
  const unsigned need = k - cnt_gt;

  const unsigned long long below = ((unsigned long long)1 << lane) - 1ull;
  unsigned rank[NE];
  unsigned base = 0;
#pragma unroll
  for (int s = 0; s < NSEG; ++s) {
    unsigned lanecnt = 0, tot = 0, own = 0;
    unsigned long long B[4];
#pragma unroll
    for (int j = 0; j < 4; ++j) {
      B[j] = __ballot(key[(s << 2) + j] == tau);
      lanecnt += (unsigned)__popcll(B[j] & below);
      tot += (unsigned)__popcll(B[j]);
    }
#pragma unroll
    for (int j = 0; j < 4; ++j) {
      rank[(s << 2) + j] = base + lanecnt + own;
      own += (key[(s << 2) + j] == tau) ? 1u : 0u;
    }
    base += tot;
  }

  bool sel[NE];
#pragma unroll
  for (int e = 0; e < NE; ++e)
    sel[e] = (key[e] > tau) | ((key[e] == tau) & (rank[e] < need));

  float lm = -INFINITY;
#pragma unroll
  for (int e = 0; e < NE; ++e) lm = fmaxf(lm, gv[e]);
  const float m = wredmax(lm);

  float ex[NE];
  float ps = 0.f;
#pragma unroll
  for (int e = 0; e < NE; ++e) {
    ex[e] = sel[e] ? __expf(gv[e] - m) : 0.f;
    ps += ex[e];
  }
  const float S = wredsum(ps);
  const float invS = 1.f / S;

  float sp[NE];
#pragma unroll
  for (int e = 0; e < NE; ++e) sp[e] = sel[e] ? av[e] * ex[e] * invS : 0.f;

  // final softmax over the FULL 1024-wide row; tail cols have sp == 0
  float lM = 0.f;
#pragma unroll
  for (int e = 0; e < NE; ++e) lM = fmaxf(lM, sp[e]);
  const float M = wredmax(lM);

  float pe[NE];
  float lz = 0.f;
#pragma unroll
  for (int e = 0; e < NE; ++e) { pe[e] = __expf(sp[e] - M); lz += pe[e]; }
  const float ez = __expf(0.f - M);                 // value at every tail column
  const float Z = wredsum(lz) + (float)(1024 - 256 * NSEG) * ez;
  const float invZ = 1.f / Z;

  // write split-bf16 [Ph|Pl] in place — only the first NSEG segments
#pragma unroll
  for (int s = 0; s < NSEG; ++s) {
    unsigned short hh[4], ll[4];
#pragma unroll
    for (int j = 0; j < 4; ++j) {
      const float p = pe[(s << 2) + j] * invZ;
      hh[j] = f2bf(p);
      ll[j] = f2bf(p - bf2f(hh[j]));
    }
    prow[(s << 6) + lane] = make_ushort4(hh[0], hh[1], hh[2], hh[3]);
    prow[256 + (s << 6) + lane] = make_ushort4(ll[0], ll[1], ll[2], ll[3]);
  }
  if (NSEG < 4) {
    if (lane == 0) CT[row] = ez * invZ;   // constant tail value for k_pv3
  }
}

__global__ __launch_bounds__(256, 4) void k_select(
    const float* __restrict__ ATT, unsigned short* __restrict__ P2,
    const float* __restrict__ NOISE, float* __restrict__ CT,
    const float* __restrict__ SR, const float* __restrict__ GT) {
  const int tid = threadIdx.x;
  const int lane = tid & 63;
  const int row = (blockIdx.x << 2) | (tid >> 6);   // t is wave-uniform
  const int t = row & 1023;
  const int h = (row >> 10) & 15;

  const float ratio = 1.f / (1.f + __expf(-SR[h]));
  const float temp = log1pf(__expf(GT[h])) + 0.1f;
  const float invtemp = 1.f / temp;
  const int kf = (int)floorf((float)(t + 1) * ratio);
  const unsigned k = (unsigned)(kf < 1 ? 1 : kf);

  const float4* arow = (const float4*)(ATT + ((size_t)row << 10));
  const float4* urow = (const float4*)(NOISE + ((size_t)row << 10));
  ushort4* prow = (ushort4*)(P2 + ((size_t)row << 11));

  switch (t >> 8) {   // wave-uniform branch
    case 0:  select_body<1>(arow, urow, prow, CT, row, t, lane, k, invtemp); break;
    case 1:  select_body<2>(arow, urow, prow, CT, row, t, lane, k, invtemp); break;
    case 2:  select_body<3>(arow, urow, prow, CT, row, t, lane, k, invtemp); break;
    default: select_body<4>(arow, urow, prow, CT, row, t, lane, k, invtemp); break;
  }
}

// ---------------- K4: Y2 = P2 @ V, K = 256*NSEG + rank-1 tail fix ----------------
// 1-D grid(512): id = xb*64 + z with xb permuted so blocks id and id+256 have
// NSEG classes summing to 7 (balanced pairs per CU). 2-phase dbuf K-loop.
__global__ __launch_bounds__(256) void k_pv3(
    const unsigned short* __restrict__ P2, const unsigned short* __restrict__ Vht,
    const unsigned short* __restrict__ Vlt, const float* __restrict__ CT,
    const float* __restrict__ SUF, unsigned short* __restrict__ Y2) {
  __shared__ unsigned short Ahs[2][128 * 32], Als[2][128 * 32],
                            Bhs[2][64 * 32], Bls[2][64 * 32];
  const int tid = threadIdx.x, lane = tid & 63, w = tid >> 6;
  const int id = blockIdx.x;
  const int z = id & 63;
  const int xb = id >> 6;                           // 0..7
  const int xcls = (xb < 4) ? xb : 11 - xb;         // pairing perm: c(id)+c(id+256)=7
  const int b = z >> 4, h = z & 15;
  const unsigned short* A = P2 + ((size_t)z * T_SEQ << 11);
  const unsigned short* Bh = Vht + ((size_t)z * HD << 10);
  const unsigned short* Bl = Vlt + ((size_t)z * HD << 10);
  const int m0 = xcls << 7;
  const int NSEG = (xcls >> 1) + 1;                 // 1..4
  const int nt = NSEG << 3;                         // K-iters = 256*NSEG/32
  const int wr = (w >> 1) << 6, wc = (w & 1) << 5;
  f32x4 acc[4][2];
#pragma unroll
  for (int i = 0; i < 4; ++i)
#pragma unroll
    for (int j = 0; j < 2; ++j) acc[i][j] = (f32x4){0.f, 0.f, 0.f, 0.f};

  const int lrow = lane >> 2, lk = (lane & 3) << 3;
  const int ra0 = (w << 5) + lrow, ra1 = ra0 + 16;
  const int rb = (w << 4) + lrow;
  const unsigned short* gah0 = A + ((size_t)(m0 + ra0) << 11) + lk;
  const unsigned short* gah1 = A + ((size_t)(m0 + ra1) << 11) + lk;
  const unsigned short* gbh = Bh + ((size_t)rb << 10) + lk;
  const unsigned short* gbl = Bl + ((size_t)rb << 10) + lk;
  const int stoffA = (w << 10) + (lane << 3);
  const int stoffB = (w << 9) + (lane << 3);
  const int fcol = lane & 15, koff = (lane >> 4) << 3;

  auto STAGE = [&](int buf, int k0) {
    gl_lds16(gah0 + k0, Ahs[buf] + stoffA);        gl_lds16(gah1 + k0, Ahs[buf] + stoffA + 512);
    gl_lds16(gah0 + 1024 + k0, Als[buf] + stoffA); gl_lds16(gah1 + 1024 + k0, Als[buf] + stoffA + 512);
    gl_lds16(gbh + k0, Bhs[buf] + stoffB);
    gl_lds16(gbl + k0, Bls[buf] + stoffB);
  };
  auto COMPUTE = [&](int buf) {
    bf16x8 afh[4], afl[4], bfh[2], bfl[2];
#pragma unroll
    for (int i = 0; i < 4; ++i) {
      const int off = ((wr + (i << 4) + fcol) << 5) + koff;
      afh[i] = *(const bf16x8*)&Ahs[buf][off];
      afl[i] = *(const bf16x8*)&Als[buf][off];
    }
#pragma unroll
    for (int j = 0; j < 2; ++j) {
      const int off = ((wc + (j << 4) + fcol) << 5) + koff;
      bfh[j] = *(const bf16x8*)&Bhs[buf][off];
      bfl[j] = *(const bf16x8*)&Bls[buf][off];
    }
#pragma unroll
    for (int i = 0; i < 4; ++i)
#pragma unroll
      for (int j = 0; j < 2; ++j) {
        acc[i][j] = __builtin_amdgcn_mfma_f32_16x16x32_bf16(afh[i], bfh[j], acc[i][j], 0, 0, 0);
        acc[i][j] = __builtin_amdgcn_mfma_f32_16x16x32_bf16(afh[i], bfl[j], acc[i][j], 0, 0, 0);
        acc[i][j] = __builtin_amdgcn_mfma_f32_16x16x32_bf16(afl[i], bfh[j], acc[i][j], 0, 0, 0);
      }
  };

  STAGE(0, 0);
  __syncthreads();
  int cur = 0;
  for (int t = 0; t < nt - 1; ++t) {
    STAGE(cur ^ 1, (t + 1) << 5);
    COMPUTE(cur);
    __syncthreads();
    cur ^= 1;
  }
  COMPUTE(cur);

  const int qd = lane >> 4;
  // constant-tail correction: Y[t,d] += CT[t] * SUF[z][NSEG-1][d]
  float ct[4][4];
  if (NSEG < 4) {
    const float* ctp = CT + ((size_t)z << 10) + m0;
#pragma unroll
    for (int i = 0; i < 4; ++i)
#pragma unroll
      for (int r = 0; r < 4; ++r)
        ct[i][r] = ctp[wr + (i << 4) + (qd << 2) + r];
  }
#pragma unroll
  for (int j = 0; j < 2; ++j) {
    const int d = wc + (j << 4) + fcol;      // 0..63
    const int c = (h << 6) + d;              // col in Y
    float sv = 0.f;
    if (NSEG < 4) sv = SUF[((size_t)z * 3 + (NSEG - 1)) * 64 + d];
#pragma unroll
    for (int i = 0; i < 4; ++i) {
#pragma unroll
      for (int r = 0; r < 4; ++r) {
        const int tq = m0 + wr + (i << 4) + (qd << 2) + r;
        float v = acc[i][j][r];
        if (NSEG < 4) v += ct[i][r] * sv;
        const unsigned short hi = f2bf(v);
        const unsigned short lo = f2bf(v - bf2f(hi));
        unsigned short* y = Y2 + (((size_t)(b * T_SEQ + tq)) << 11) + c;
        y[0] = hi; y[1024] = lo;
      }
    }
  }
}

// ---------------- K5: OUT = Y2 @ [Wph+Wpl]^T + b_proj (2-phase dbuf) ----------------
__global__ __launch_bounds__(256) void k_proj3(
    const unsigned short* __restrict__ A, const unsigned short* __restrict__ Bh,
    const unsigned short* __restrict__ Bl, const float* __restrict__ bias,
    float* __restrict__ OUT) {
  __shared__ unsigned short Ahs[2][128 * 32], Als[2][128 * 32],
                            Bhs[2][128 * 32], Bls[2][128 * 32];
  const int tid = threadIdx.x, lane = tid & 63, w = tid >> 6;
  const int m0 = blockIdx.y * 128, n0 = blockIdx.x * 128;
  const int wr = (w >> 1) << 6, wc = (w & 1) << 6;
  f32x4 acc[4][4];
#pragma unroll
  for (int i = 0; i < 4; ++i)
#pragma unroll
    for (int j = 0; j < 4; ++j) acc[i][j] = (f32x4){0.f, 0.f, 0.f, 0.f};

  const int lrow = lane >> 2, lk = (lane & 3) << 3;
  const int r0 = (w << 5) + lrow, r1 = r0 + 16;
  const unsigned short* gah0 = A + ((size_t)(m0 + r0) << 11) + lk;
  const unsigned short* gah1 = A + ((size_t)(m0 + r1) << 11) + lk;
  const unsigned short* gbh0 = Bh + ((size_t)(n0 + r0) << 10) + lk;
  const unsigned short* gbh1 = Bh + ((size_t)(n0 + r1) << 10) + lk;
  const unsigned short* gbl0 = Bl + ((size_t)(n0 + r0) << 10) + lk;
  const unsigned short* gbl1 = Bl + ((size_t)(n0 + r1) << 10) + lk;
  const int stoff = (w << 10) + (lane << 3);
  const int fcol = lane & 15, koff = (lane >> 4) << 3;

  auto STAGE = [&](int buf, int k0) {
    gl_lds16(gah0 + k0, Ahs[buf] + stoff);        gl_lds16(gah1 + k0, Ahs[buf] + stoff + 512);
    gl_lds16(gah0 + 1024 + k0, Als[buf] + stoff); gl_lds16(gah1 + 1024 + k0, Als[buf] + stoff + 512);
    gl_lds16(gbh0 + k0, Bhs[buf] + stoff);        gl_lds16(gbh1 + k0, Bhs[buf] + stoff + 512);
    gl_lds16(gbl0 + k0, Bls[buf] + stoff);        gl_lds16(gbl1 + k0, Bls[buf] + stoff + 512);
  };
  auto COMPUTE = [&](int buf) {
    bf16x8 afh[4], afl[4], bfh[4], bfl[4];
#pragma unroll
    for (int i = 0; i < 4; ++i) {
      const int off = ((wr + (i << 4) + fcol) << 5) + koff;
      afh[i] = *(const bf16x8*)&Ahs[buf][off];
      afl[i] = *(const bf16x8*)&Als[buf][off];
    }
#pragma unroll
    for (int j = 0; j < 4; ++j) {
      const int off = ((wc + (j << 4) + fcol) << 5) + koff;
      bfh[j] = *(const bf16x8*)&Bhs[buf][off];
      bfl[j] = *(const bf16x8*)&Bls[buf][off];
    }
#pragma unroll
    for (int i = 0; i < 4; ++i)
#pragma unroll
      for (int j = 0; j < 4; ++j) {
        acc[i][j] = __builtin_amdgcn_mfma_f32_16x16x32_bf16(afh[i], bfh[j], acc[i][j], 0, 0, 0);
        acc[i][j] = __builtin_amdgcn_mfma_f32_16x16x32_bf16(afh[i], bfl[j], acc[i][j], 0, 0, 0);
        acc[i][j] = __builtin_amdgcn_mfma_f32_16x16x32_bf16(afl[i], bfh[j], acc[i][j], 0, 0, 0);
      }
  };

  STAGE(0, 0);
  __syncthreads();
  int cur = 0;
  for (int t = 0; t < 31; ++t) {
    STAGE(cur ^ 1, (t + 1) << 5);
    COMPUTE(cur);
    __syncthreads();
    cur ^= 1;
  }
  COMPUTE(cur);

  const int qd = lane >> 4;
#pragma unroll
  for (int j = 0; j < 4; ++j) {
    const int n = n0 + wc + (j << 4) + fcol;
    const float bv = bias[n];
#pragma unroll
    for (int i = 0; i < 4; ++i)
#pragma unroll
      for (int r = 0; r < 4; ++r) {
        const int m = m0 + wr + (i << 4) + (qd << 2) + r;
        OUT[((size_t)m << 10) + n] = acc[i][j][r] + bv;
      }
  }
}

extern "C" void kernel_launch(void* const* d_in, const int* in_sizes, int n_in,
                              void* d_out, int out_size, void* d_ws, size_t ws_size,
                              hipStream_t stream) {
  const float* x      = (const float*)d_in[0];
  const float* W_attn = (const float*)d_in[1];
  const float* b_attn = (const float*)d_in[2];
  const float* W_proj = (const float*)d_in[3];
  const float* b_proj = (const float*)d_in[4];
  const float* sr     = (const float*)d_in[5];
  const float* gt     = (const float*)d_in[6];
  const float* noise  = (const float*)d_in[7];

  char* base = (char*)d_ws;
  // [0, 268435456): ATT fp32 (later overwritten in-place by P2 bf16).
  //   Prep aliases inside (dead after k_qkv3): A2q, Bhq, Blq.
  float*          ATT = (float*)base;
  unsigned short* A2q = (unsigned short*)base;                    // 16 MB
  unsigned short* Bhq = (unsigned short*)(base + 16777216);       //  6 MB
  unsigned short* Blq = (unsigned short*)(base + 23068672);       //  6 MB
  unsigned short* P2  = (unsigned short*)base;                    // in-place over ATT
  // [268435456, +16 MB): Q2; after k_att3 reused for W_proj split
  unsigned short* Q2  = (unsigned short*)(base + 268435456);
  unsigned short* Wph = (unsigned short*)(base + 268435456);
  unsigned short* Wpl = (unsigned short*)(base + 270532608);
  // [285212672, +16 MB): Kht+Klt; after k_att3 reused for Y2
  unsigned short* Kht = (unsigned short*)(base + 285212672);
  unsigned short* Klt = (unsigned short*)(base + 293601280);
  unsigned short* Y2  = (unsigned short*)(base + 285212672);
  // [301989888, +16 MB): Vht+Vlt
  unsigned short* Vht = (unsigned short*)(base + 301989888);
  unsigned short* Vlt = (unsigned short*)(base + 310378496);
  // [318767104, +256 KB): CT per-row tail constant; then SUF [64][3][64] f32
  float* CT  = (float*)(base + 318767104);
  float* SUF = (float*)(base + 319029248);
  float* OUT = (float*)d_out;

  k_split_a2<<<dim3(4096),     256, 0, stream>>>(x, A2q);
  k_split_b2<<<dim3(96, 32),   256, 0, stream>>>(W_attn, Bhq, Blq, 3072, 1024);
  k_qkv3    <<<dim3(24, 32),   256, 0, stream>>>(A2q, Bhq, Blq, b_attn, Q2, Kht, Klt, Vht, Vlt);
  k_vsuf    <<<dim3(64),       256, 0, stream>>>(Vht, Vlt, SUF);
  k_att3    <<<dim3(36, 64),   256, 0, stream>>>(Q2, Kht, Klt, ATT);
  k_split_b2<<<dim3(32, 32),   256, 0, stream>>>(W_proj, Wph, Wpl, 1024, 1024);
  k_select  <<<dim3(16384),    256, 0, stream>>>(ATT, P2, noise, CT, sr, gt);
  k_pv3     <<<dim3(512),      256, 0, stream>>>(P2, Vht, Vlt, CT, SUF, Y2);
  k_proj3   <<<dim3(8, 32),    256, 0, stream>>>(Y2, Wph, Wpl, b_proj, OUT);
}